// Round 8
// baseline (258.449 us; speedup 1.0000x reference)
//
#include <hip/hip_runtime.h>
#include <hip/hip_fp16.h>
#include <stdint.h>

// Problem constants: Xp(16384,3) X(8192,3) W(64,8192) eps scalar -> out(16384,64)
#define M_ROWS 16384
#define N_PTS  8192
#define K_OUT  64

typedef _Float16       h2    __attribute__((ext_vector_type(2)));
typedef unsigned short u16x2 __attribute__((ext_vector_type(2)));
typedef _Float16       f16x8 __attribute__((ext_vector_type(8)));
typedef float          f32x4 __attribute__((ext_vector_type(4)));

union AF { f16x8 v; uint4 q; uint32_t u[4]; h2 h[4]; };

__device__ __forceinline__ h2 pkrtz2(float a, float b) {
    return __builtin_bit_cast(h2, __builtin_amdgcn_cvt_pkrtz(a, b));
}
__device__ __forceinline__ uint32_t pkrtz(float a, float b) {
    return __builtin_bit_cast(uint32_t, __builtin_amdgcn_cvt_pkrtz(a, b));
}

// packed fast sqrt(t), t in [1, ~512]: per-half rsqrt bit-seed + 1 reassociated
// Newton. 6 packed VALU ops / 2 phis. Rel err <= ~3e-3 (validated r5-r7, absmax 8).
__device__ __forceinline__ h2 pk_sqrt_fast(h2 t, h2 mhf, h2 c15) {
    u16x2 u = __builtin_bit_cast(u16x2, t);
    u16x2 r0u = (u16x2){0x59BA, 0x59BA} - (u >> 1);
    h2 r0 = __builtin_bit_cast(h2, r0u);
    h2 y = t * r0;
    h2 p = y * r0;
    h2 k = __builtin_elementwise_fma(p, mhf, c15);
    return y * k;
}

// ---------------- prep ----------------
// blocks [0,256):   W -> fragment-linear f16 Wt (B-frag order for 16x16x32):
//                   Wt uint4 idx (b*4+kt)*64+lane = W[kt*16+(lane&15)][b*32+(lane>>4)*8+j]
// blocks [256,272): coord streams as packed-f16 pairs (4096 dwords each):
//                   Cx = -2*eps*x, Cy, Cz, Cc = |eps*x|^2 + 1
__global__ __launch_bounds__(256) void rbf_prep(
    const float* __restrict__ Wf, const float* __restrict__ X,
    const float* __restrict__ epsp,
    uint4* __restrict__ Wt, uint32_t* __restrict__ Cx,
    uint32_t* __restrict__ Cy, uint32_t* __restrict__ Cz,
    uint32_t* __restrict__ Cc)
{
    const int bid = blockIdx.x, tid = threadIdx.x;
    if (bid < 256) {
        const int kt = tid >> 6, lane = tid & 63;
        const int l15 = lane & 15, g = lane >> 4;
        const int row = kt * 16 + l15;
        const int col = bid * 32 + g * 8;
        const float4* src = (const float4*)(Wf + row * N_PTS + col);
        const float4 w0 = src[0], w1 = src[1];
        uint4 p;
        p.x = pkrtz(w0.x, w0.y);
        p.y = pkrtz(w0.z, w0.w);
        p.z = pkrtz(w1.x, w1.y);
        p.w = pkrtz(w1.z, w1.w);
        Wt[(bid * 4 + kt) * 64 + lane] = p;
    } else {
        const int n = (bid - 256) * 256 + tid;       // pair index [0, 4096)
        const float e = *epsp;
        const float2 A = *(const float2*)(X + 6 * n);      // x0 y0
        const float2 B = *(const float2*)(X + 6 * n + 2);  // z0 x1
        const float2 C = *(const float2*)(X + 6 * n + 4);  // y1 z1
        const float x0 = A.x * e, y0 = A.y * e, z0 = B.x * e;
        const float x1 = B.y * e, y1 = C.x * e, z1 = C.y * e;
        Cx[n] = pkrtz(-2.0f * x0, -2.0f * x1);
        Cy[n] = pkrtz(-2.0f * y0, -2.0f * y1);
        Cz[n] = pkrtz(-2.0f * z0, -2.0f * z1);
        Cc[n] = pkrtz(fmaf(x0, x0, fmaf(y0, y0, fmaf(z0, z0, 1.0f))),
                      fmaf(x1, x1, fmaf(y1, y1, fmaf(z1, z1, 1.0f))));
    }
}

// ---------------- main: split-N in-block, f16 LDS cross-wave reduce, no atomics ----
// 512 blocks x 512 threads. LDS cut to 32 KB (f16 partials) so 4 blocks/CU
// = 8 waves/SIMD = 100% occupancy; __launch_bounds__(512,8) caps VGPR at 64
// (r7's identical loop body compiled to 56). Loop body unchanged from r7.
__global__ __launch_bounds__(512, 8) void rbf_main(
    const float* __restrict__ Xp, const uint4* __restrict__ Wt,
    const uint32_t* __restrict__ Cx, const uint32_t* __restrict__ Cy,
    const uint32_t* __restrict__ Cz, const uint32_t* __restrict__ Cc,
    const float* __restrict__ epsp, float* __restrict__ out)
{
    __shared__ __align__(16) _Float16 sR[8 * 32 * 64];   // 32 KB: [wave][row(32)][col(64)]

    const int tid  = threadIdx.x;
    const int lane = tid & 63;
    const int wv   = tid >> 6;        // 0..7 = n-chunk
    const int m    = lane & 15;
    const int g    = lane >> 4;

    const int rowbase = blockIdx.x * 32;

    // per-lane row geometry for 2 tiles (rows rowbase + t*16 + m), f16 splat pairs
    const float e = *epsp;
    h2 pxk[2], pyk[2], pzk[2], aak[2];
    #pragma unroll
    for (int t = 0; t < 2; ++t) {
        const int r = rowbase + t * 16 + m;
        const float px = Xp[3 * r + 0] * e;
        const float py = Xp[3 * r + 1] * e;
        const float pz = Xp[3 * r + 2] * e;
        const float a  = fmaf(px, px, fmaf(py, py, pz * pz));
        pxk[t] = pkrtz2(px, px);
        pyk[t] = pkrtz2(py, py);
        pzk[t] = pkrtz2(pz, pz);
        aak[t] = pkrtz2(a, a);
    }
    const h2 mhf = {(_Float16)-0.5f, (_Float16)-0.5f};
    const h2 c15 = {(_Float16)1.5f, (_Float16)1.5f};

    f32x4 acc[2][4];
    #pragma unroll
    for (int t = 0; t < 2; ++t)
        #pragma unroll
        for (int kt = 0; kt < 4; ++kt)
            acc[t][kt] = (f32x4){0.f, 0.f, 0.f, 0.f};

    // uniform bases (wv, block only) — divergent part is a FIXED lane offset
    const uint32_t* cxp = Cx + wv * 512 + g * 4;   // + s*16 (imm)
    const uint32_t* cyp = Cy + wv * 512 + g * 4;
    const uint32_t* czp = Cz + wv * 512 + g * 4;
    const uint32_t* ccp = Cc + wv * 512 + g * 4;
    const uint4*    wp  = Wt + wv * 8192 + lane;   // + s*256 (SGPR) + kt*64 (imm)

    #pragma unroll 8
    for (int s = 0; s < 32; ++s) {
        const uint4 vx = *(const uint4*)(cxp + s * 16);
        const uint4 vy = *(const uint4*)(cyp + s * 16);
        const uint4 vz = *(const uint4*)(czp + s * 16);
        const uint4 vc = *(const uint4*)(ccp + s * 16);

        AF wf0, wf1, wf2, wf3;
        wf0.q = wp[s * 256];
        wf1.q = wp[s * 256 + 64];
        wf2.q = wp[s * 256 + 128];
        wf3.q = wp[s * 256 + 192];

        const h2 cx[4] = {__builtin_bit_cast(h2, vx.x), __builtin_bit_cast(h2, vx.y),
                          __builtin_bit_cast(h2, vx.z), __builtin_bit_cast(h2, vx.w)};
        const h2 cy[4] = {__builtin_bit_cast(h2, vy.x), __builtin_bit_cast(h2, vy.y),
                          __builtin_bit_cast(h2, vy.z), __builtin_bit_cast(h2, vy.w)};
        const h2 cz[4] = {__builtin_bit_cast(h2, vz.x), __builtin_bit_cast(h2, vz.y),
                          __builtin_bit_cast(h2, vz.z), __builtin_bit_cast(h2, vz.w)};
        const h2 cc[4] = {__builtin_bit_cast(h2, vc.x), __builtin_bit_cast(h2, vc.y),
                          __builtin_bit_cast(h2, vc.z), __builtin_bit_cast(h2, vc.w)};

        #pragma unroll
        for (int t = 0; t < 2; ++t) {
            AF af;
            #pragma unroll
            for (int j = 0; j < 4; ++j) {
                h2 d = cc[j] + aak[t];
                d = __builtin_elementwise_fma(pxk[t], cx[j], d);
                d = __builtin_elementwise_fma(pyk[t], cy[j], d);
                d = __builtin_elementwise_fma(pzk[t], cz[j], d);
                af.h[j] = pk_sqrt_fast(d, mhf, c15);
            }
            acc[t][0] = __builtin_amdgcn_mfma_f32_16x16x32_f16(af.v, wf0.v, acc[t][0], 0, 0, 0);
            acc[t][1] = __builtin_amdgcn_mfma_f32_16x16x32_f16(af.v, wf1.v, acc[t][1], 0, 0, 0);
            acc[t][2] = __builtin_amdgcn_mfma_f32_16x16x32_f16(af.v, wf2.v, acc[t][2], 0, 0, 0);
            acc[t][3] = __builtin_amdgcn_mfma_f32_16x16x32_f16(af.v, wf3.v, acc[t][3], 0, 0, 0);
        }
    }

    // ---- cross-wave reduction through LDS (f16 partials) ----
    // acc[t][kt][reg] = partial out[rowbase + t*16 + g*4 + reg][kt*16 + m]
    {
        _Float16* base = sR + wv * 2048;
        #pragma unroll
        for (int t = 0; t < 2; ++t)
            #pragma unroll
            for (int kt = 0; kt < 4; ++kt)
                #pragma unroll
                for (int reg = 0; reg < 4; ++reg)
                    base[(t * 16 + g * 4 + reg) * 64 + kt * 16 + m] =
                        (_Float16)acc[t][kt][reg];
    }
    __syncthreads();

    // 512 threads: thread -> (row = tid>>4, kq = tid&15); sum 8 waves in f32, store
    {
        const int row = tid >> 4;
        const int kq  = tid & 15;
        const _Float16* p = sR + row * 64 + kq * 4;
        float4 s0 = make_float4(0.f, 0.f, 0.f, 0.f);
        #pragma unroll
        for (int w = 0; w < 8; ++w) {
            const uint2 pv = *(const uint2*)(p + w * 2048);
            const h2 lo = __builtin_bit_cast(h2, pv.x);
            const h2 hi = __builtin_bit_cast(h2, pv.y);
            s0.x += (float)lo[0]; s0.y += (float)lo[1];
            s0.z += (float)hi[0]; s0.w += (float)hi[1];
        }
        *(float4*)(out + (rowbase + row) * K_OUT + kq * 4) = s0;
    }
}

extern "C" void kernel_launch(void* const* d_in, const int* in_sizes, int n_in,
                              void* d_out, int out_size, void* d_ws, size_t ws_size,
                              hipStream_t stream) {
    (void)in_sizes; (void)n_in; (void)out_size; (void)ws_size;
    const float* Xp  = (const float*)d_in[0];   // (16384,3)
    const float* X   = (const float*)d_in[1];   // (8192,3)
    const float* Wf  = (const float*)d_in[2];   // (64,8192)
    const float* eps = (const float*)d_in[3];   // scalar
    float* out = (float*)d_out;                 // (16384,64)

    // ws: Wt (fragment-linear f16 W) 1 MiB | Cx,Cy,Cz,Cc 16 KiB each
    uint4*    Wt = (uint4*)d_ws;
    uint32_t* Cx = (uint32_t*)((char*)d_ws + (1u << 20));
    uint32_t* Cy = Cx + 4096;
    uint32_t* Cz = Cy + 4096;
    uint32_t* Cc = Cz + 4096;

    rbf_prep<<<dim3(272), dim3(256), 0, stream>>>(Wf, X, eps, Wt, Cx, Cy, Cz, Cc);
    rbf_main<<<dim3(M_ROWS / 32), dim3(512), 0, stream>>>(
        Xp, Wt, Cx, Cy, Cz, Cc, eps, out);
}

// Round 9
// 128.408 us; speedup vs baseline: 2.0127x; 2.0127x over previous
//
#include <hip/hip_runtime.h>
#include <hip/hip_fp16.h>
#include <stdint.h>

// Problem constants: Xp(16384,3) X(8192,3) W(64,8192) eps scalar -> out(16384,64)
#define M_ROWS 16384
#define N_PTS  8192
#define K_OUT  64

typedef _Float16       h2    __attribute__((ext_vector_type(2)));
typedef unsigned short u16x2 __attribute__((ext_vector_type(2)));
typedef _Float16       f16x8 __attribute__((ext_vector_type(8)));
typedef float          f32x4 __attribute__((ext_vector_type(4)));

union AF { f16x8 v; uint4 q; uint32_t u[4]; h2 h[4]; };

__device__ __forceinline__ h2 pkrtz2(float a, float b) {
    return __builtin_bit_cast(h2, __builtin_amdgcn_cvt_pkrtz(a, b));
}
__device__ __forceinline__ uint32_t pkrtz(float a, float b) {
    return __builtin_bit_cast(uint32_t, __builtin_amdgcn_cvt_pkrtz(a, b));
}

// packed fast sqrt(t), t in [1, ~512]: per-half rsqrt bit-seed + 1 reassociated
// Newton. 6 packed VALU ops / 2 phis. Rel err <= ~3e-3 (validated r5-r8, absmax 8).
__device__ __forceinline__ h2 pk_sqrt_fast(h2 t, h2 mhf, h2 c15) {
    u16x2 u = __builtin_bit_cast(u16x2, t);
    u16x2 r0u = (u16x2){0x59BA, 0x59BA} - (u >> 1);
    h2 r0 = __builtin_bit_cast(h2, r0u);
    h2 y = t * r0;
    h2 p = y * r0;
    h2 k = __builtin_elementwise_fma(p, mhf, c15);
    return y * k;
}

// ---------------- prep (unchanged from r7) ----------------
__global__ __launch_bounds__(256) void rbf_prep(
    const float* __restrict__ Wf, const float* __restrict__ X,
    const float* __restrict__ epsp,
    uint4* __restrict__ Wt, uint32_t* __restrict__ Cx,
    uint32_t* __restrict__ Cy, uint32_t* __restrict__ Cz,
    uint32_t* __restrict__ Cc)
{
    const int bid = blockIdx.x, tid = threadIdx.x;
    if (bid < 256) {
        const int kt = tid >> 6, lane = tid & 63;
        const int l15 = lane & 15, g = lane >> 4;
        const int row = kt * 16 + l15;
        const int col = bid * 32 + g * 8;
        const float4* src = (const float4*)(Wf + row * N_PTS + col);
        const float4 w0 = src[0], w1 = src[1];
        uint4 p;
        p.x = pkrtz(w0.x, w0.y);
        p.y = pkrtz(w0.z, w0.w);
        p.z = pkrtz(w1.x, w1.y);
        p.w = pkrtz(w1.z, w1.w);
        Wt[(bid * 4 + kt) * 64 + lane] = p;
    } else {
        const int n = (bid - 256) * 256 + tid;       // pair index [0, 4096)
        const float e = *epsp;
        const float2 A = *(const float2*)(X + 6 * n);      // x0 y0
        const float2 B = *(const float2*)(X + 6 * n + 2);  // z0 x1
        const float2 C = *(const float2*)(X + 6 * n + 4);  // y1 z1
        const float x0 = A.x * e, y0 = A.y * e, z0 = B.x * e;
        const float x1 = B.y * e, y1 = C.x * e, z1 = C.y * e;
        Cx[n] = pkrtz(-2.0f * x0, -2.0f * x1);
        Cy[n] = pkrtz(-2.0f * y0, -2.0f * y1);
        Cz[n] = pkrtz(-2.0f * z0, -2.0f * z1);
        Cc[n] = pkrtz(fmaf(x0, x0, fmaf(y0, y0, fmaf(z0, z0, 1.0f))),
                      fmaf(x1, x1, fmaf(y1, y1, fmaf(z1, z1, 1.0f))));
    }
}

// ---------------- main: T=1/wave for <=64 unified regs, 8 waves/SIMD ----------
// 512 blocks x 1024 threads (16 waves). Block owns rows [bid*32, bid*32+32).
// Wave (rt = wv&1, nc = wv>>1): row-tile rt (16 rows), points [nc*1024,(nc+1)*1024)
// = 32 iters of 32 pts, 4 MFMA each. Accumulator = 16 regs (T=1) so the wave
// fits the 64-reg budget for 8 waves/SIMD (r8 lesson: t=2 demand ~90 -> spill).
// Epilogue: 8 nc-partials summed through 64 KB LDS; 2 blocks/CU = 100% occupancy.
__global__ __launch_bounds__(1024, 8) void rbf_main(
    const float* __restrict__ Xp, const uint4* __restrict__ Wt,
    const uint32_t* __restrict__ Cx, const uint32_t* __restrict__ Cy,
    const uint32_t* __restrict__ Cz, const uint32_t* __restrict__ Cc,
    const float* __restrict__ epsp, float* __restrict__ out)
{
    __shared__ __align__(16) float sR[8 * 32 * 64];   // 64 KB: [nc][row(32)][col(64)]

    const int tid  = threadIdx.x;
    const int lane = tid & 63;
    const int wv   = tid >> 6;        // 0..15
    const int rt   = wv & 1;          // row-tile
    const int nc   = wv >> 1;         // n-chunk 0..7
    const int m    = lane & 15;
    const int g    = lane >> 4;

    const int rowbase = blockIdx.x * 32 + rt * 16;

    // per-lane row geometry (row rowbase + m), f16 splat pairs — 4 regs
    const float e = *epsp;
    h2 pxk, pyk, pzk, aak;
    {
        const int r = rowbase + m;
        const float px = Xp[3 * r + 0] * e;
        const float py = Xp[3 * r + 1] * e;
        const float pz = Xp[3 * r + 2] * e;
        const float a  = fmaf(px, px, fmaf(py, py, pz * pz));
        pxk = pkrtz2(px, px);
        pyk = pkrtz2(py, py);
        pzk = pkrtz2(pz, pz);
        aak = pkrtz2(a, a);
    }
    const h2 mhf = {(_Float16)-0.5f, (_Float16)-0.5f};
    const h2 c15 = {(_Float16)1.5f, (_Float16)1.5f};

    f32x4 acc0 = {0.f, 0.f, 0.f, 0.f};
    f32x4 acc1 = acc0, acc2 = acc0, acc3 = acc0;

    // uniform bases; divergent part is a FIXED lane offset
    const uint32_t* cxp = Cx + nc * 512 + g * 4;   // + s*16 dwords (imm <= 1984 B)
    const uint32_t* cyp = Cy + nc * 512 + g * 4;
    const uint32_t* czp = Cz + nc * 512 + g * 4;
    const uint32_t* ccp = Cc + nc * 512 + g * 4;
    const uint4*    wp  = Wt + nc * 8192 + lane;   // + s*256 (SGPR) + kt*64 (imm)

    #pragma unroll 4
    for (int s = 0; s < 32; ++s) {
        const uint4 vx = *(const uint4*)(cxp + s * 16);
        const uint4 vy = *(const uint4*)(cyp + s * 16);
        const uint4 vz = *(const uint4*)(czp + s * 16);
        const uint4 vc = *(const uint4*)(ccp + s * 16);

        AF wf0, wf1, wf2, wf3;
        wf0.q = wp[s * 256];
        wf1.q = wp[s * 256 + 64];
        wf2.q = wp[s * 256 + 128];
        wf3.q = wp[s * 256 + 192];

        const h2 cx[4] = {__builtin_bit_cast(h2, vx.x), __builtin_bit_cast(h2, vx.y),
                          __builtin_bit_cast(h2, vx.z), __builtin_bit_cast(h2, vx.w)};
        const h2 cy[4] = {__builtin_bit_cast(h2, vy.x), __builtin_bit_cast(h2, vy.y),
                          __builtin_bit_cast(h2, vy.z), __builtin_bit_cast(h2, vy.w)};
        const h2 cz[4] = {__builtin_bit_cast(h2, vz.x), __builtin_bit_cast(h2, vz.y),
                          __builtin_bit_cast(h2, vz.z), __builtin_bit_cast(h2, vz.w)};
        const h2 cc[4] = {__builtin_bit_cast(h2, vc.x), __builtin_bit_cast(h2, vc.y),
                          __builtin_bit_cast(h2, vc.z), __builtin_bit_cast(h2, vc.w)};

        AF af;
        #pragma unroll
        for (int j = 0; j < 4; ++j) {
            h2 d = cc[j] + aak;
            d = __builtin_elementwise_fma(pxk, cx[j], d);
            d = __builtin_elementwise_fma(pyk, cy[j], d);
            d = __builtin_elementwise_fma(pzk, cz[j], d);
            af.h[j] = pk_sqrt_fast(d, mhf, c15);
        }
        acc0 = __builtin_amdgcn_mfma_f32_16x16x32_f16(af.v, wf0.v, acc0, 0, 0, 0);
        acc1 = __builtin_amdgcn_mfma_f32_16x16x32_f16(af.v, wf1.v, acc1, 0, 0, 0);
        acc2 = __builtin_amdgcn_mfma_f32_16x16x32_f16(af.v, wf2.v, acc2, 0, 0, 0);
        acc3 = __builtin_amdgcn_mfma_f32_16x16x32_f16(af.v, wf3.v, acc3, 0, 0, 0);
    }

    // ---- cross-chunk reduction through LDS ----
    // acc{kt}[reg] = partial out[rowbase + g*4 + reg][kt*16 + m] for chunk nc
    {
        float* base = sR + nc * 2048 + (rt * 16 + g * 4) * 64 + m;
        #pragma unroll
        for (int reg = 0; reg < 4; ++reg) {
            base[reg * 64 +  0] = acc0[reg];
            base[reg * 64 + 16] = acc1[reg];
            base[reg * 64 + 32] = acc2[reg];
            base[reg * 64 + 48] = acc3[reg];
        }
    }
    __syncthreads();

    // threads 0..511: (row = tid>>4 in [0,32), kq = tid&15), sum 8 chunks, store
    if (tid < 512) {
        const int row = tid >> 4;
        const int kq  = tid & 15;
        const float* p = sR + row * 64 + kq * 4;
        float4 s0 = *(const float4*)(p);
        #pragma unroll
        for (int w = 1; w < 8; ++w) {
            const float4 sw = *(const float4*)(p + w * 2048);
            s0.x += sw.x; s0.y += sw.y; s0.z += sw.z; s0.w += sw.w;
        }
        *(float4*)(out + (blockIdx.x * 32 + row) * K_OUT + kq * 4) = s0;
    }
}

extern "C" void kernel_launch(void* const* d_in, const int* in_sizes, int n_in,
                              void* d_out, int out_size, void* d_ws, size_t ws_size,
                              hipStream_t stream) {
    (void)in_sizes; (void)n_in; (void)out_size; (void)ws_size;
    const float* Xp  = (const float*)d_in[0];   // (16384,3)
    const float* X   = (const float*)d_in[1];   // (8192,3)
    const float* Wf  = (const float*)d_in[2];   // (64,8192)
    const float* eps = (const float*)d_in[3];   // scalar
    float* out = (float*)d_out;                 // (16384,64)

    // ws: Wt (fragment-linear f16 W) 1 MiB | Cx,Cy,Cz,Cc 16 KiB each
    uint4*    Wt = (uint4*)d_ws;
    uint32_t* Cx = (uint32_t*)((char*)d_ws + (1u << 20));
    uint32_t* Cy = Cx + 4096;
    uint32_t* Cz = Cy + 4096;
    uint32_t* Cc = Cz + 4096;

    rbf_prep<<<dim3(272), dim3(256), 0, stream>>>(Wf, X, eps, Wt, Cx, Cy, Cz, Cc);
    rbf_main<<<dim3(M_ROWS / 32), dim3(1024), 0, stream>>>(
        Xp, Wt, Cx, Cy, Cz, Cc, eps, out);
}